// Round 6
// baseline (136.904 us; speedup 1.0000x reference)
//
#include <hip/hip_runtime.h>
#include <hip/hip_bf16.h>

// Problem constants (from reference)
constexpr int T_ = 4;
constexpr int B_ = 8;
constexpr int N_ = 5000;
constexpr int E_ = 80000;
constexpr int TBN = T_ * B_ * N_;   // 160000
constexpr int NXCD = 8;

// layer-kernel geometry: 4 lanes per node, 64 nodes per 256-thread block
constexpr int NPB = 64;                       // nodes per block
constexpr int CH  = (N_ + NPB - 1) / NPB;     // 79 chunks per graph
constexpr int GRP = T_ * B_ / NXCD;           // 4 graphs per XCD
constexpr int LB  = NXCD * CH * GRP;          // 2528 blocks

// bf16 pack/unpack (round-to-nearest-ish via +0x8000)
__device__ __forceinline__ unsigned bf16pack2(float lo, float hi) {
    unsigned ul = (__float_as_uint(lo) + 0x8000u) >> 16;
    unsigned uh = (__float_as_uint(hi) + 0x8000u) & 0xffff0000u;
    return uh | ul;
}
__device__ __forceinline__ void bf16unpack2(unsigned u, float& lo, float& hi) {
    lo = __uint_as_float(u << 16);
    hi = __uint_as_float(u & 0xffff0000u);
}

// ---------------------------------------------------------------------------
// CSR build kernels (edges shared across all T*B graphs)
// ---------------------------------------------------------------------------
__global__ void k_degree(const int* __restrict__ dst, int* __restrict__ deg) {
    int e = blockIdx.x * 256 + threadIdx.x;
    if (e < E_) atomicAdd(&deg[dst[e]], 1);
}

__global__ void k_scan(const int* __restrict__ deg, int* __restrict__ row_start) {
    __shared__ int sums[256];
    const int tid = threadIdx.x;
    const int per = 20;                    // 256*20 = 5120 >= N
    const int base = tid * per;
    int local = 0;
    for (int i = 0; i < per; ++i) {
        int idx = base + i;
        if (idx < N_) local += deg[idx];
    }
    sums[tid] = local;
    __syncthreads();
    for (int off = 1; off < 256; off <<= 1) {
        int v = 0;
        if (tid >= off) v = sums[tid - off];
        __syncthreads();
        if (tid >= off) sums[tid] += v;
        __syncthreads();
    }
    int running = sums[tid] - local;       // exclusive prefix
    for (int i = 0; i < per; ++i) {
        int idx = base + i;
        if (idx < N_) {
            row_start[idx] = running;
            running += deg[idx];
        }
    }
    if (tid == 255) row_start[N_] = sums[255];
}

__global__ void k_scatter(const int* __restrict__ src, const int* __restrict__ dst,
                          const int* __restrict__ row_start, int* __restrict__ cursor,
                          int* __restrict__ csr_src) {
    int e = blockIdx.x * 256 + threadIdx.x;
    if (e < E_) {
        int d = dst[e];
        int pos = atomicAdd(&cursor[d], 1);
        csr_src[row_start[d] + pos] = src[e];
    }
}

// ---------------------------------------------------------------------------
// Degree counting-sort -> perm[slot] = node. Within-bin order is arbitrary
// (atomic), but per-node math is identical regardless of placement, so the
// final output is bit-deterministic. Purpose: uniform loop lengths within a
// wave (less exec-mask divergence in k_layer).
// ---------------------------------------------------------------------------
__global__ void k_perm(const int* __restrict__ deg, int* __restrict__ perm) {
    __shared__ int hist[64];
    __shared__ int base[64];
    const int tid = threadIdx.x;
    if (tid < 64) hist[tid] = 0;
    __syncthreads();
    for (int idx = tid; idx < N_; idx += 256) {
        int d = min(deg[idx], 63);
        atomicAdd(&hist[d], 1);
    }
    __syncthreads();
    if (tid == 0) {
        int running = 0;
        for (int b = 0; b < 64; ++b) { base[b] = running; running += hist[b]; }
    }
    __syncthreads();
    if (tid < 64) hist[tid] = 0;           // reuse as cursor
    __syncthreads();
    for (int idx = tid; idx < N_; idx += 256) {
        int d = min(deg[idx], 63);
        int pos = atomicAdd(&hist[d], 1);
        perm[base[d] + pos] = idx;
    }
}

// ---------------------------------------------------------------------------
// xs4 build
// ---------------------------------------------------------------------------
__global__ void k_init(const float* __restrict__ xs, float4* __restrict__ xs4) {
    int g = blockIdx.x * 256 + threadIdx.x;   // 625*256 == TBN exact
    xs4[g] = make_float4(xs[3*g], xs[3*g+1], xs[3*g+2], 0.0f);
}

// ---------------------------------------------------------------------------
// Fused layer kernel. 4 lanes/node (degree-sorted via perm), edges striped
// across the quad, 3-stage software pipeline: csr index prefetched 2 iters
// ahead, gathers (xs4 + gs/charge) issued 1 iter ahead, compute current.
// State: h fp32[TBN][16] (own quarter), gs/gd bf16[TBN][16].
// LYR==0: gs0[s]=c_s*P, gd0=c_n*Q+b1 inline; per-edge gather = charge (4B).
// HAS_NEXT tail feature-split across quad (hnew quarter -> shfl -> proj).
// ---------------------------------------------------------------------------
template <int LYR, bool HAS_NEXT>
__global__ __launch_bounds__(256, 4) void k_layer(
        const float4* __restrict__ xs4, const float* __restrict__ charges,
        const float* __restrict__ vs, const float* __restrict__ W_embed,
        const float* __restrict__ W1, const float* __restrict__ b1,
        const float* __restrict__ W2, const float* __restrict__ b2,
        const float* __restrict__ Wv,
        const int* __restrict__ row_start, const int* __restrict__ csr_src,
        const int* __restrict__ perm,
        float* __restrict__ h, const uint4* __restrict__ gs_in,
        uint2* __restrict__ gs_out, unsigned* __restrict__ gd,
        float* __restrict__ vec) {
    __shared__ float s_w1e[16], s_wv[16], s_b2[16], s_b1[16], s_b1n[16];
    __shared__ float s_W2[256];
    __shared__ float s_W1sn[256];          // next layer rows 0..15
    __shared__ float s_W1dn[256];          // next layer rows 16..31
    __shared__ float s_P[16], s_Q[16], s_rwe[16];   // layer-0 collapse
    const int tid = threadIdx.x;
    if (tid < 16) {
        s_w1e[tid] = W1[LYR * 528 + 512 + tid];
        s_wv[tid]  = Wv[LYR * 16 + tid];
        s_b2[tid]  = b2[LYR * 16 + tid];
        s_b1[tid]  = b1[LYR * 16 + tid];
        if (HAS_NEXT) s_b1n[tid] = b1[(LYR + 1) * 16 + tid];
    }
    s_W2[tid] = W2[LYR * 256 + tid];
    if (HAS_NEXT) {
        s_W1sn[tid] = W1[(LYR + 1) * 528 + tid];
        s_W1dn[tid] = W1[(LYR + 1) * 528 + 256 + tid];
    }
    if (LYR == 0 && tid < 16) {
        float accP = 0.0f, accQ = 0.0f;
        for (int j = 0; j < 16; ++j) {
            float r = fmaxf(W_embed[j], 0.0f);
            accP += r * W1[j * 16 + tid];          // W1s layer0
            accQ += r * W1[256 + j * 16 + tid];    // W1d layer0
        }
        s_P[tid] = accP; s_Q[tid] = accQ;
        s_rwe[tid] = fmaxf(W_embed[tid], 0.0f);
    }
    __syncthreads();

    // XCD swizzle bijection over 2528 = 8 * 316 blocks
    const int bid   = blockIdx.x;
    const int xcd   = bid & 7;
    const int j     = bid >> 3;            // 0..315
    const int tb    = xcd + NXCD * (j / CH);
    const int chunk = j % CH;
    const int idx   = chunk * NPB + (tid >> 2);
    const int q     = tid & 3;
    if (idx >= N_) return;                 // whole quad exits together; no syncs below
    const int node  = perm[idx];           // degree-sorted

    const int g = tb * N_ + node;
    const size_t nb = (size_t)tb * N_;
    const float* cb = charges + (tb % B_) * N_;

    const float4 xn = xs4[g];

    // gdn: full 16, per lane
    float gdn[16];
    float c0 = 0.0f;
    if (LYR == 0) {
        c0 = cb[node];
#pragma unroll
        for (int f = 0; f < 16; ++f) gdn[f] = c0 * s_Q[f] + s_b1[f];
    } else {
        const uint4* gdp = (const uint4*)gd + (size_t)g * 2;
        uint4 da = gdp[0], db = gdp[1];
        bf16unpack2(da.x, gdn[0], gdn[1]);  bf16unpack2(da.y, gdn[2], gdn[3]);
        bf16unpack2(da.z, gdn[4], gdn[5]);  bf16unpack2(da.w, gdn[6], gdn[7]);
        bf16unpack2(db.x, gdn[8], gdn[9]);  bf16unpack2(db.y, gdn[10], gdn[11]);
        bf16unpack2(db.z, gdn[12], gdn[13]); bf16unpack2(db.w, gdn[14], gdn[15]);
    }

    float agg[16];
#pragma unroll
    for (int f = 0; f < 16; ++f) agg[f] = 0.0f;
    float av0 = 0.0f, av1 = 0.0f, av2 = 0.0f;

    const int rs = row_start[node];
    const int re = row_start[node + 1];

    // ---- 3-stage pipelined edge loop (edges striped across the quad) ----
    int e = rs + q;
    // csr for iter0 and iter1 (clamped: csr_src has E_ valid entries)
    int sCur  = csr_src[min(e, E_ - 1)];
    int sNext = csr_src[min(e + 4, E_ - 1)];
    // gathers for iter0
    size_t si = nb + (size_t)sCur;
    float4 xc = xs4[si];
    float  cs = 0.0f;
    uint4  ga, gb;
    if (LYR == 0) cs = cb[sCur];
    else { ga = gs_in[si * 2]; gb = gs_in[si * 2 + 1]; }

    while (e < re) {
        // stage A: csr prefetch 2 iterations ahead
        int s3 = csr_src[min(e + 8, E_ - 1)];
        // stage B: gathers for next iteration (sNext was loaded 1 iter ago)
        size_t siN = nb + (size_t)sNext;
        float4 xcN = xs4[siN];
        float  csN = 0.0f;
        uint4  gaN, gbN;
        if (LYR == 0) csN = cb[sNext];
        else { gaN = gs_in[siN * 2]; gbN = gs_in[siN * 2 + 1]; }

        // stage C: compute current edge
        float d0 = xn.x - xc.x;
        float d1 = xn.y - xc.y;
        float d2v = xn.z - xc.z;
        float dd = d0*d0 + d1*d1 + d2v*d2v;

        float gsf[16];
        if (LYR == 0) {
#pragma unroll
            for (int f = 0; f < 16; ++f) gsf[f] = cs * s_P[f];
        } else {
            bf16unpack2(ga.x, gsf[0], gsf[1]);  bf16unpack2(ga.y, gsf[2], gsf[3]);
            bf16unpack2(ga.z, gsf[4], gsf[5]);  bf16unpack2(ga.w, gsf[6], gsf[7]);
            bf16unpack2(gb.x, gsf[8], gsf[9]);  bf16unpack2(gb.y, gsf[10], gsf[11]);
            bf16unpack2(gb.z, gsf[12], gsf[13]); bf16unpack2(gb.w, gsf[14], gsf[15]);
        }

        float sval = 0.0f;
#pragma unroll
        for (int f = 0; f < 16; ++f) {
            float mv = fmaxf(__builtin_fmaf(dd, s_w1e[f], gdn[f]) + gsf[f], 0.0f);
            if (HAS_NEXT) agg[f] += mv;
            sval = __builtin_fmaf(mv, s_wv[f], sval);
        }
        av0 = __builtin_fmaf(d0, sval, av0);
        av1 = __builtin_fmaf(d1, sval, av1);
        av2 = __builtin_fmaf(d2v, sval, av2);

        // rotate pipeline
        e += 4;
        sNext = s3;
        xc = xcN; cs = csN; ga = gaN; gb = gbN;
    }

    // quad reduce of av (lanes of a quad are consecutive & quad-aligned)
    av0 += __shfl_xor(av0, 1); av0 += __shfl_xor(av0, 2);
    av1 += __shfl_xor(av1, 1); av1 += __shfl_xor(av1, 2);
    av2 += __shfl_xor(av2, 1); av2 += __shfl_xor(av2, 2);

    if (q < 3) {
        float myav = (q == 0) ? av0 : ((q == 1) ? av1 : av2);
        size_t vi = (size_t)g * 3 + q;
        float base = (LYR == 0) ? vs[vi] : vec[vi];
        vec[vi] = base + myav;
    }

    if (HAS_NEXT) {
        // full agg across quad (hnew needs all 16 j)
#pragma unroll
        for (int f = 0; f < 16; ++f) {
            agg[f] += __shfl_xor(agg[f], 1);
            agg[f] += __shfl_xor(agg[f], 2);
        }

        // hn quarter for this lane
        float hq[4];
        if (LYR == 0) {
#pragma unroll
            for (int k = 0; k < 4; ++k) hq[k] = c0 * s_rwe[q * 4 + k];
        } else {
            float4 hv = ((const float4*)h)[(size_t)g * 4 + q];
            hq[0] = hv.x; hq[1] = hv.y; hq[2] = hv.z; hq[3] = hv.w;
        }

        // hnew quarter: hq += relu(agg @ W2 + b2) for own 4 features
        float acc[4];
#pragma unroll
        for (int k = 0; k < 4; ++k) acc[k] = s_b2[q * 4 + k];
#pragma unroll
        for (int jj = 0; jj < 16; ++jj) {
            float aj = agg[jj];
#pragma unroll
            for (int k = 0; k < 4; ++k)
                acc[k] = __builtin_fmaf(aj, s_W2[jj * 16 + q * 4 + k], acc[k]);
        }
#pragma unroll
        for (int k = 0; k < 4; ++k) hq[k] += fmaxf(acc[k], 0.0f);

        // exchange quarters -> full hnew
        const int lane = tid & 63;
        const int lbase = lane & ~3;
        float hfull[16];
#pragma unroll
        for (int sq = 0; sq < 4; ++sq) {
#pragma unroll
            for (int k = 0; k < 4; ++k)
                hfull[sq * 4 + k] = __shfl(hq[k], lbase + sq, 64);
        }

        // next-layer projections, own 4 columns
        float gso[4], gdo[4];
#pragma unroll
        for (int k = 0; k < 4; ++k) { gso[k] = 0.0f; gdo[k] = s_b1n[q * 4 + k]; }
#pragma unroll
        for (int jj = 0; jj < 16; ++jj) {
            float hj = hfull[jj];
#pragma unroll
            for (int k = 0; k < 4; ++k) {
                gso[k] = __builtin_fmaf(hj, s_W1sn[jj * 16 + q * 4 + k], gso[k]);
                gdo[k] = __builtin_fmaf(hj, s_W1dn[jj * 16 + q * 4 + k], gdo[k]);
            }
        }

        ((float4*)h)[(size_t)g * 4 + q] = make_float4(hq[0], hq[1], hq[2], hq[3]);
        gs_out[(size_t)g * 4 + q] = make_uint2(bf16pack2(gso[0], gso[1]),
                                               bf16pack2(gso[2], gso[3]));
        ((uint2*)gd)[(size_t)g * 4 + q] = make_uint2(bf16pack2(gdo[0], gdo[1]),
                                                     bf16pack2(gdo[2], gdo[3]));
    }
}

// ---------------------------------------------------------------------------
// Final: out[b*N+n] = sum_t softmax(theta)[t] * (vec[t,b,n] + xs[t,b,n])
// ---------------------------------------------------------------------------
__global__ void k_final(const float* __restrict__ xs, const float* __restrict__ vec,
                        const float* __restrict__ theta, float* __restrict__ out) {
    int g = blockIdx.x * 256 + threadIdx.x;
    if (g >= B_ * N_) return;
    float t0 = theta[0], t1 = theta[1], t2 = theta[2], t3 = theta[3];
    float mx = fmaxf(fmaxf(t0, t1), fmaxf(t2, t3));
    float e0 = expf(t0 - mx), e1 = expf(t1 - mx), e2 = expf(t2 - mx), e3 = expf(t3 - mx);
    float inv = 1.0f / (e0 + e1 + e2 + e3);
    float w[4] = {e0 * inv, e1 * inv, e2 * inv, e3 * inv};

    int b = g / N_;
    int n = g - b * N_;
    float o0 = 0.0f, o1 = 0.0f, o2 = 0.0f;
#pragma unroll
    for (int t = 0; t < 4; ++t) {
        size_t idx = ((size_t)(t * B_ + b) * N_ + n) * 3;
        o0 += w[t] * (vec[idx+0] + xs[idx+0]);
        o1 += w[t] * (vec[idx+1] + xs[idx+1]);
        o2 += w[t] * (vec[idx+2] + xs[idx+2]);
    }
    out[(size_t)g*3+0] = o0;
    out[(size_t)g*3+1] = o1;
    out[(size_t)g*3+2] = o2;
}

// ---------------------------------------------------------------------------
extern "C" void kernel_launch(void* const* d_in, const int* in_sizes, int n_in,
                              void* d_out, int out_size, void* d_ws, size_t ws_size,
                              hipStream_t stream) {
    const float* xs       = (const float*)d_in[0];
    const float* vs       = (const float*)d_in[1];
    const float* charges  = (const float*)d_in[2];
    const int*   edge_src = (const int*)d_in[3];
    const int*   edge_dst = (const int*)d_in[4];
    const float* theta    = (const float*)d_in[5];
    const float* W_embed  = (const float*)d_in[6];
    const float* W1       = (const float*)d_in[7];
    const float* b1       = (const float*)d_in[8];
    const float* W2       = (const float*)d_in[9];
    const float* b2       = (const float*)d_in[10];
    const float* Wv       = (const float*)d_in[11];
    float* out = (float*)d_out;

    // workspace layout (256B aligned)
    char* w = (char*)d_ws;
    size_t off = 0;
    auto take = [&](size_t bytes) {
        size_t o = off;
        off = (off + bytes + 255) & ~(size_t)255;
        return o;
    };
    int*      deg       = (int*)(w + take((size_t)N_ * 4));
    int*      cursor    = (int*)(w + take((size_t)N_ * 4));
    int*      row_start = (int*)(w + take((size_t)(N_ + 1) * 4));
    int*      csr_src   = (int*)(w + take((size_t)E_ * 4));
    int*      perm      = (int*)(w + take((size_t)N_ * 4));
    float*    h         = (float*)(w + take((size_t)TBN * 16 * 4));
    unsigned* gsA       = (unsigned*)(w + take((size_t)TBN * 32));   // bf16 x16
    unsigned* gsB       = (unsigned*)(w + take((size_t)TBN * 32));
    unsigned* gd        = (unsigned*)(w + take((size_t)TBN * 32));
    float*    vec       = (float*)(w + take((size_t)TBN * 3 * 4));
    float4*   xs4       = (float4*)(w + take((size_t)TBN * 16));
    (void)ws_size;

    // single memset covers deg + pad + cursor (adjacent in layout)
    size_t zlen = (size_t)((char*)cursor - (char*)deg) + (size_t)N_ * 4;
    hipMemsetAsync(deg, 0, zlen, stream);

    const int eb = (E_ + 255) / 256;        // 313
    k_degree<<<eb, 256, 0, stream>>>(edge_dst, deg);
    k_scan<<<1, 256, 0, stream>>>(deg, row_start);
    k_perm<<<1, 256, 0, stream>>>(deg, perm);
    k_scatter<<<eb, 256, 0, stream>>>(edge_src, edge_dst, row_start, cursor, csr_src);

    k_init<<<TBN / 256, 256, 0, stream>>>(xs, xs4);

    // layer 0 writes gsA+gd (for layer 1); layer 1 reads gsA, writes gsB+gd;
    // layer 2 reads gsB+gd, writes only vec
    k_layer<0, true ><<<LB, 256, 0, stream>>>(xs4, charges, vs, W_embed, W1, b1, W2, b2, Wv,
                                              row_start, csr_src, perm, h, nullptr,
                                              (uint2*)gsA, gd, vec);
    k_layer<1, true ><<<LB, 256, 0, stream>>>(xs4, charges, vs, W_embed, W1, b1, W2, b2, Wv,
                                              row_start, csr_src, perm, h, (const uint4*)gsA,
                                              (uint2*)gsB, gd, vec);
    k_layer<2, false><<<LB, 256, 0, stream>>>(xs4, charges, vs, W_embed, W1, b1, W2, b2, Wv,
                                              row_start, csr_src, perm, h, (const uint4*)gsB,
                                              nullptr, gd, vec);

    const int fb = (B_ * N_ + 255) / 256;   // 157
    k_final<<<fb, 256, 0, stream>>>(xs, vec, theta, out);
}